// Round 5
// baseline (409.731 us; speedup 1.0000x reference)
//
#include <hip/hip_runtime.h>
#include <hip/hip_bf16.h>
#include <math.h>

#define N_NODES 50000
#define N_EDGES 500000
#define C_DIM 128

typedef __attribute__((ext_vector_type(8))) short bf8;
typedef __attribute__((ext_vector_type(4))) float f32x4;

__device__ __forceinline__ float bflo(unsigned u) { return __uint_as_float(u << 16); }
__device__ __forceinline__ float bfhi(unsigned u) { return __uint_as_float(u & 0xffff0000u); }
__device__ __forceinline__ unsigned short f2bfu(float f) {
    __hip_bfloat16 h = __float2bfloat16(f);
    unsigned short u;
    __builtin_memcpy(&u, &h, 2);
    return u;
}
__device__ __forceinline__ unsigned packbf(float a, float b) {
    return ((unsigned)f2bfu(b) << 16) | f2bfu(a);
}

// ---------------- graph preprocessing ----------------

__global__ void count_deg(const int* __restrict__ row, const int* __restrict__ col,
                          int* __restrict__ dout, int* __restrict__ din, int e) {
    int i = blockIdx.x * blockDim.x + threadIdx.x;
    if (i >= e) return;
    atomicAdd(&dout[row[i]], 1);
    atomicAdd(&din[col[i]], 1);
}

__global__ void scan_block(const int* __restrict__ counts, int* __restrict__ excl,
                           int* __restrict__ blocksums, int n) {
    __shared__ int tmp[1024];
    int tid = threadIdx.x;
    int gid = blockIdx.x * 1024 + tid;
    int v = (gid < n) ? counts[gid] : 0;
    tmp[tid] = v;
    __syncthreads();
    for (int off = 1; off < 1024; off <<= 1) {
        int t = (tid >= off) ? tmp[tid - off] : 0;
        __syncthreads();
        tmp[tid] += t;
        __syncthreads();
    }
    int incl = tmp[tid];
    if (gid < n) excl[gid] = incl - v;
    if (tid == 1023) blocksums[blockIdx.x] = incl;
}

__global__ void scan_sums(int* __restrict__ blocksums, int nb) {
    __shared__ int tmp[64];
    int tid = threadIdx.x;
    int v = (tid < nb) ? blocksums[tid] : 0;
    tmp[tid] = v;
    __syncthreads();
    for (int off = 1; off < 64; off <<= 1) {
        int t = (tid >= off) ? tmp[tid - off] : 0;
        __syncthreads();
        tmp[tid] += t;
        __syncthreads();
    }
    if (tid < nb) blocksums[tid] = tmp[tid] - v;
}

__global__ void scan_add(int* __restrict__ rowptr, const int* __restrict__ blocksums,
                         int* __restrict__ cursor, const int* __restrict__ dout,
                         const int* __restrict__ din, float2* __restrict__ winv,
                         int n, int e_total) {
    int gid = blockIdx.x * blockDim.x + threadIdx.x;
    if (gid < n) {
        int v = rowptr[gid] + blocksums[gid >> 10];
        rowptr[gid] = v;
        cursor[gid] = v;
        winv[gid] = make_float2(1.0f / (float)dout[gid], 1.0f / (float)din[gid]);
    }
    if (gid == n) rowptr[n] = e_total;
}

__global__ void build_csr(const int* __restrict__ row, const int* __restrict__ col,
                          const float2* __restrict__ winv,
                          int* __restrict__ cursor, int* __restrict__ src,
                          float2* __restrict__ w, int e) {
    int i = blockIdx.x * blockDim.x + threadIdx.x;
    if (i >= e) return;
    int r = row[i], c = col[i];
    int pos = atomicAdd(&cursor[c], 1);
    src[pos] = r;
    w[pos] = winv[r];
}

// ---------------- weight packing (bf16, [n][640], interleaved k-order) ------
__device__ __forceinline__ float wraw(const float* W, int d, int kk, int k, int j) {
    return W[((d * 3 + kk) * 128 + k) * 64 + j];
}

__global__ void pack_weights(const float* __restrict__ Wz, const float* __restrict__ Wr,
                             const float* __restrict__ Wh,
                             unsigned short* __restrict__ Wzr_t,   // [128][640]
                             unsigned short* __restrict__ Wh_t) {  // [64][640]
    int i = blockIdx.x * blockDim.x + threadIdx.x;
    if (i < 128 * 640) {
        int k = i % 640;
        int nn = i / 640;
        const float* W = (nn < 64) ? Wz : Wr;
        int j = nn & 63;
        float v;
        if (k < 128) {
            v = wraw(W, 0, 0, k, j) + wraw(W, 1, 0, k, j);
        } else {
            int k2 = k - 128;
            int kk = (k2 >= 256) ? 2 : 1;
            int k3 = k2 & 255;
            int p = k3 >> 2, sub = k3 & 3;
            v = wraw(W, sub >> 1, kk, 2 * p + (sub & 1), j);
        }
        Wzr_t[i] = f2bfu(v);
    } else if (i < 128 * 640 + 64 * 640) {
        int i2 = i - 128 * 640;
        int k = i2 % 640;
        int j = i2 / 640;
        float v;
        if (k < 64) {
            v = wraw(Wh, 0, 0, k, j) + wraw(Wh, 1, 0, k, j);
        } else if (k < 320) {
            int k2 = k - 64;
            int kk = (k2 >= 128) ? 2 : 1;
            int k3 = k2 & 127;
            int p = k3 >> 2, sub = k3 & 3;
            v = wraw(Wh, sub >> 1, kk, 2 * p + (sub & 1), j);
        } else if (k < 384) {
            int rr = k - 320;
            v = wraw(Wh, 0, 0, 64 + rr, j) + wraw(Wh, 1, 0, 64 + rr, j);
        } else {
            int k2 = k - 384;
            int kk = (k2 >= 128) ? 2 : 1;
            int k3 = k2 & 127;
            int p = k3 >> 2, sub = k3 & 3;
            v = wraw(Wh, sub >> 1, kk, 64 + 2 * p + (sub & 1), j);
        }
        Wh_t[i2] = f2bfu(v);
    }
}

// ---------------- concat ----------------

__global__ void concat_xh(const float* __restrict__ X, const float* __restrict__ H,
                          unsigned short* __restrict__ XH, int n) {
    int i = blockIdx.x * blockDim.x + threadIdx.x;
    if (i >= n * C_DIM) return;
    int r = i >> 7, c = i & 127;
    float v = (c < 64) ? X[r * 64 + c] : H[r * 64 + (c - 64)];
    XH[i] = f2bfu(v);
}

// ---------------- diffusion props ----------------
// P layout [n][256]: pair p (0..63): cols 4p..4p+3 = {o(2p), o(2p+1), i(2p), i(2p+1)}
// Q layout [n][128]: same with 32 pairs.

__global__ void prop1_128(const unsigned short* __restrict__ S,
                          const int* __restrict__ rowptr, const int* __restrict__ src,
                          const float2* __restrict__ w,
                          unsigned short* __restrict__ P1, int n) {
    int tid = blockIdx.x * blockDim.x + threadIdx.x;
    int lane = tid & 63;
    int node = ((tid >> 6) << 1) + (lane >> 5);
    int p = lane & 31;
    if (node >= n) return;
    int beg = rowptr[node], end = rowptr[node + 1];
    float ao0 = 0.f, ao1 = 0.f, ao2 = 0.f, ao3 = 0.f;
    float ai0 = 0.f, ai1 = 0.f, ai2 = 0.f, ai3 = 0.f;
    int j = beg;
#define P1STEP(s_, w_) {                                                     \
        uint2 u = *(const uint2*)(S + (size_t)(s_) * 128 + 4 * p);           \
        float c0 = bflo(u.x), c1 = bfhi(u.x), c2 = bflo(u.y), c3 = bfhi(u.y);\
        ao0 = fmaf(w_.x, c0, ao0); ao1 = fmaf(w_.x, c1, ao1);                \
        ao2 = fmaf(w_.x, c2, ao2); ao3 = fmaf(w_.x, c3, ao3);                \
        ai0 = fmaf(w_.y, c0, ai0); ai1 = fmaf(w_.y, c1, ai1);                \
        ai2 = fmaf(w_.y, c2, ai2); ai3 = fmaf(w_.y, c3, ai3); }
    for (; j + 4 <= end; j += 4) {
        int s0 = src[j], s1 = src[j + 1], s2 = src[j + 2], s3 = src[j + 3];
        float2 w0 = w[j], w1 = w[j + 1], w2 = w[j + 2], w3 = w[j + 3];
        P1STEP(s0, w0); P1STEP(s1, w1); P1STEP(s2, w2); P1STEP(s3, w3);
    }
    for (; j < end; ++j) {
        int s = src[j]; float2 wv = w[j];
        P1STEP(s, wv);
    }
#undef P1STEP
    uint4 o;
    o.x = packbf(ao0, ao1); o.y = packbf(ai0, ai1);
    o.z = packbf(ao2, ao3); o.w = packbf(ai2, ai3);
    *(uint4*)(P1 + (size_t)node * 256 + 8 * p) = o;
}

__global__ void prop2_128(const unsigned short* __restrict__ P1,
                          const unsigned short* __restrict__ Xc,
                          const int* __restrict__ rowptr, const int* __restrict__ src,
                          const float2* __restrict__ w,
                          unsigned short* __restrict__ P2, int n) {
    int tid = blockIdx.x * blockDim.x + threadIdx.x;
    int lane = tid & 63;
    int node = ((tid >> 6) << 1) + (lane >> 5);
    int p = lane & 31;
    if (node >= n) return;
    int beg = rowptr[node], end = rowptr[node + 1];
    float oa = 0.f, ob = 0.f, oc = 0.f, od = 0.f;
    float ia = 0.f, ib = 0.f, ic = 0.f, id = 0.f;
    int j = beg;
#define P2STEP(s_, w_) {                                                     \
        uint4 v = *(const uint4*)(P1 + (size_t)(s_) * 256 + 8 * p);          \
        oa = fmaf(w_.x, bflo(v.x), oa); ob = fmaf(w_.x, bfhi(v.x), ob);      \
        ia = fmaf(w_.y, bflo(v.y), ia); ib = fmaf(w_.y, bfhi(v.y), ib);      \
        oc = fmaf(w_.x, bflo(v.z), oc); od = fmaf(w_.x, bfhi(v.z), od);      \
        ic = fmaf(w_.y, bflo(v.w), ic); id = fmaf(w_.y, bfhi(v.w), id); }
    for (; j + 4 <= end; j += 4) {
        int s0 = src[j], s1 = src[j + 1], s2 = src[j + 2], s3 = src[j + 3];
        float2 w0 = w[j], w1 = w[j + 1], w2 = w[j + 2], w3 = w[j + 3];
        P2STEP(s0, w0); P2STEP(s1, w1); P2STEP(s2, w2); P2STEP(s3, w3);
    }
    for (; j < end; ++j) {
        int s = src[j]; float2 wv = w[j];
        P2STEP(s, wv);
    }
#undef P2STEP
    uint2 ux = *(const uint2*)(Xc + (size_t)node * 128 + 4 * p);
    float xa = bflo(ux.x), xb = bfhi(ux.x), xc = bflo(ux.y), xd = bfhi(ux.y);
    uint4 o;
    o.x = packbf(2.f * oa - xa, 2.f * ob - xb);
    o.y = packbf(2.f * ia - xa, 2.f * ib - xb);
    o.z = packbf(2.f * oc - xc, 2.f * od - xd);
    o.w = packbf(2.f * ic - xc, 2.f * id - xd);
    *(uint4*)(P2 + (size_t)node * 256 + 8 * p) = o;
}

__global__ void prop1_64(const unsigned short* __restrict__ HR,
                         const int* __restrict__ rowptr, const int* __restrict__ src,
                         const float2* __restrict__ w,
                         unsigned short* __restrict__ Q1, int n) {
    int tid = blockIdx.x * blockDim.x + threadIdx.x;
    int lane = tid & 63;
    int node = ((tid >> 6) << 2) + (lane >> 4);
    int p = lane & 15;
    if (node >= n) return;
    int beg = rowptr[node], end = rowptr[node + 1];
    float ao0 = 0.f, ao1 = 0.f, ao2 = 0.f, ao3 = 0.f;
    float ai0 = 0.f, ai1 = 0.f, ai2 = 0.f, ai3 = 0.f;
    int j = beg;
#define Q1STEP(s_, w_) {                                                     \
        uint2 u = *(const uint2*)(HR + (size_t)(s_) * 64 + 4 * p);           \
        float c0 = bflo(u.x), c1 = bfhi(u.x), c2 = bflo(u.y), c3 = bfhi(u.y);\
        ao0 = fmaf(w_.x, c0, ao0); ao1 = fmaf(w_.x, c1, ao1);                \
        ao2 = fmaf(w_.x, c2, ao2); ao3 = fmaf(w_.x, c3, ao3);                \
        ai0 = fmaf(w_.y, c0, ai0); ai1 = fmaf(w_.y, c1, ai1);                \
        ai2 = fmaf(w_.y, c2, ai2); ai3 = fmaf(w_.y, c3, ai3); }
    for (; j + 4 <= end; j += 4) {
        int s0 = src[j], s1 = src[j + 1], s2 = src[j + 2], s3 = src[j + 3];
        float2 w0 = w[j], w1 = w[j + 1], w2 = w[j + 2], w3 = w[j + 3];
        Q1STEP(s0, w0); Q1STEP(s1, w1); Q1STEP(s2, w2); Q1STEP(s3, w3);
    }
    for (; j < end; ++j) {
        int s = src[j]; float2 wv = w[j];
        Q1STEP(s, wv);
    }
#undef Q1STEP
    uint4 o;
    o.x = packbf(ao0, ao1); o.y = packbf(ai0, ai1);
    o.z = packbf(ao2, ao3); o.w = packbf(ai2, ai3);
    *(uint4*)(Q1 + (size_t)node * 128 + 8 * p) = o;
}

__global__ void prop2_64(const unsigned short* __restrict__ Q1,
                         const unsigned short* __restrict__ HR,
                         const int* __restrict__ rowptr, const int* __restrict__ src,
                         const float2* __restrict__ w,
                         unsigned short* __restrict__ Q2, int n) {
    int tid = blockIdx.x * blockDim.x + threadIdx.x;
    int lane = tid & 63;
    int node = ((tid >> 6) << 2) + (lane >> 4);
    int p = lane & 15;
    if (node >= n) return;
    int beg = rowptr[node], end = rowptr[node + 1];
    float oa = 0.f, ob = 0.f, oc = 0.f, od = 0.f;
    float ia = 0.f, ib = 0.f, ic = 0.f, id = 0.f;
    int j = beg;
#define Q2STEP(s_, w_) {                                                     \
        uint4 v = *(const uint4*)(Q1 + (size_t)(s_) * 128 + 8 * p);          \
        oa = fmaf(w_.x, bflo(v.x), oa); ob = fmaf(w_.x, bfhi(v.x), ob);      \
        ia = fmaf(w_.y, bflo(v.y), ia); ib = fmaf(w_.y, bfhi(v.y), ib);      \
        oc = fmaf(w_.x, bflo(v.z), oc); od = fmaf(w_.x, bfhi(v.z), od);      \
        ic = fmaf(w_.y, bflo(v.w), ic); id = fmaf(w_.y, bfhi(v.w), id); }
    for (; j + 4 <= end; j += 4) {
        int s0 = src[j], s1 = src[j + 1], s2 = src[j + 2], s3 = src[j + 3];
        float2 w0 = w[j], w1 = w[j + 1], w2 = w[j + 2], w3 = w[j + 3];
        Q2STEP(s0, w0); Q2STEP(s1, w1); Q2STEP(s2, w2); Q2STEP(s3, w3);
    }
    for (; j < end; ++j) {
        int s = src[j]; float2 wv = w[j];
        Q2STEP(s, wv);
    }
#undef Q2STEP
    uint2 ux = *(const uint2*)(HR + (size_t)node * 64 + 4 * p);
    float xa = bflo(ux.x), xb = bfhi(ux.x), xc = bflo(ux.y), xd = bfhi(ux.y);
    uint4 o;
    o.x = packbf(2.f * oa - xa, 2.f * ob - xb);
    o.y = packbf(2.f * ia - xa, 2.f * ib - xb);
    o.z = packbf(2.f * oc - xc, 2.f * od - xd);
    o.w = packbf(2.f * ic - xc, 2.f * id - xd);
    *(uint4*)(Q2 + (size_t)node * 128 + 8 * p) = o;
}

// ---------------- MFMA GEMMs (register-resident B, no LDS, no barriers) -----
// mfma_f32_16x16x32_bf16: A[m=lane&15][k=quad*8+j]; B[k=quad*8+j][n=lane&15];
// C/D: col=lane&15, row=quad*4+reg.

// ZR: block = 64 rows x 128 cols; wave = 64 rows x 32 cols (ngrp = wid).
// K=640 in 20 ksteps of 32: ks 0-3 XH, 4-11 P1, 12-19 P2. B held in VGPRs
// per K-half (20 frags = 80 VGPRs).
__global__ __launch_bounds__(256) void gemm_zr_mfma(
    const unsigned short* __restrict__ XH, const unsigned short* __restrict__ P1,
    const unsigned short* __restrict__ P2,
    const unsigned short* __restrict__ Wt, const float* __restrict__ bz,
    const float* __restrict__ br, const float* __restrict__ H,
    float* __restrict__ Zf, unsigned short* __restrict__ HR, int n) {
    int tid = threadIdx.x;
    int lane = tid & 63;
    int ngrp = tid >> 6;                 // 0..3 -> 32-col group
    int rowbase = blockIdx.x * 64;
    int lr = lane & 15, quad = lane >> 4;

    const unsigned short* A0[4];
    const unsigned short* A1[4];
    const unsigned short* A2[4];
#pragma unroll
    for (int mt = 0; mt < 4; ++mt) {
        int r = rowbase + mt * 16 + lr;
        if (r >= n) r = n - 1;
        A0[mt] = XH + (size_t)r * 128 + quad * 8;
        A1[mt] = P1 + (size_t)r * 256 + quad * 8;
        A2[mt] = P2 + (size_t)r * 256 + quad * 8;
    }
    const unsigned short* Wb = Wt + (size_t)(ngrp * 32 + lr) * 640 + quad * 8;

    f32x4 zero = {0.f, 0.f, 0.f, 0.f};
    f32x4 acc[4][2];
#pragma unroll
    for (int a = 0; a < 4; ++a)
#pragma unroll
        for (int b = 0; b < 2; ++b) acc[a][b] = zero;

#pragma unroll
    for (int kh = 0; kh < 2; ++kh) {
        bf8 Breg[20];
#pragma unroll
        for (int kl = 0; kl < 10; ++kl) {
            int ks = kh * 10 + kl;
#pragma unroll
            for (int nt = 0; nt < 2; ++nt)
                Breg[kl * 2 + nt] = *(const bf8*)(Wb + (size_t)nt * 16 * 640 + ks * 32);
        }
#pragma unroll
        for (int kl = 0; kl < 10; ++kl) {
            int ks = kh * 10 + kl;
#pragma unroll
            for (int mt = 0; mt < 4; ++mt) {
                const unsigned short* ap =
                    (ks < 4)  ? (A0[mt] + ks * 32) :
                    (ks < 12) ? (A1[mt] + (ks - 4) * 32) :
                                (A2[mt] + (ks - 12) * 32);
                bf8 a = *(const bf8*)ap;
#pragma unroll
                for (int nt = 0; nt < 2; ++nt)
                    acc[mt][nt] = __builtin_amdgcn_mfma_f32_16x16x32_bf16(
                        a, Breg[kl * 2 + nt], acc[mt][nt], 0, 0, 0);
            }
        }
    }
#pragma unroll
    for (int mt = 0; mt < 4; ++mt)
#pragma unroll
        for (int reg = 0; reg < 4; ++reg) {
            int r = rowbase + mt * 16 + quad * 4 + reg;
            if (r >= n) continue;
#pragma unroll
            for (int nt = 0; nt < 2; ++nt) {
                int cidx = ngrp * 32 + nt * 16 + lr;
                float bias = (cidx < 64) ? bz[cidx] : br[cidx - 64];
                float v = acc[mt][nt][reg] + bias;
                float s = 1.f / (1.f + expf(-v));
                if (cidx < 64) {
                    Zf[(size_t)r * 64 + cidx] = s;
                } else {
                    int c2 = cidx - 64;
                    HR[(size_t)r * 64 + c2] = f2bfu(H[(size_t)r * 64 + c2] * s);
                }
            }
        }
}

// H~: block = 64 rows x 64 cols; wave = 32 rows x 32 cols
// (mhalf = wid&1 row-half, ngrp = wid>>1 col-group).
// ksteps: 0-1 XH(s128), 2-5 P1(s256), 6-9 P2(s256), 10-11 HR(s64),
//         12-15 Q1(s128), 16-19 Q2(s128).
__global__ __launch_bounds__(256) void gemm_h_mfma(
    const unsigned short* __restrict__ XH, const unsigned short* __restrict__ P1,
    const unsigned short* __restrict__ P2, const unsigned short* __restrict__ HR,
    const unsigned short* __restrict__ Q1, const unsigned short* __restrict__ Q2,
    const unsigned short* __restrict__ Wt, const float* __restrict__ bh,
    const float* __restrict__ Zf, const float* __restrict__ H,
    float* __restrict__ out, int n) {
    int tid = threadIdx.x;
    int lane = tid & 63;
    int wid = tid >> 6;
    int mhalf = wid & 1, ngrp = wid >> 1;
    int rowbase = blockIdx.x * 64 + mhalf * 32;
    int lr = lane & 15, quad = lane >> 4;

    const unsigned short* S0[2];
    const unsigned short* S1[2];
    const unsigned short* S2[2];
    const unsigned short* S3[2];
    const unsigned short* S4[2];
    const unsigned short* S5[2];
#pragma unroll
    for (int mt = 0; mt < 2; ++mt) {
        int r = rowbase + mt * 16 + lr;
        if (r >= n) r = n - 1;
        S0[mt] = XH + (size_t)r * 128 + quad * 8;
        S1[mt] = P1 + (size_t)r * 256 + quad * 8;
        S2[mt] = P2 + (size_t)r * 256 + quad * 8;
        S3[mt] = HR + (size_t)r * 64 + quad * 8;
        S4[mt] = Q1 + (size_t)r * 128 + quad * 8;
        S5[mt] = Q2 + (size_t)r * 128 + quad * 8;
    }
    const unsigned short* Wb = Wt + (size_t)(ngrp * 32 + lr) * 640 + quad * 8;

    f32x4 zero = {0.f, 0.f, 0.f, 0.f};
    f32x4 acc[2][2];
#pragma unroll
    for (int a = 0; a < 2; ++a)
#pragma unroll
        for (int b = 0; b < 2; ++b) acc[a][b] = zero;

#pragma unroll
    for (int kh = 0; kh < 2; ++kh) {
        bf8 Breg[20];
#pragma unroll
        for (int kl = 0; kl < 10; ++kl) {
            int ks = kh * 10 + kl;
#pragma unroll
            for (int nt = 0; nt < 2; ++nt)
                Breg[kl * 2 + nt] = *(const bf8*)(Wb + (size_t)nt * 16 * 640 + ks * 32);
        }
#pragma unroll
        for (int kl = 0; kl < 10; ++kl) {
            int ks = kh * 10 + kl;
#pragma unroll
            for (int mt = 0; mt < 2; ++mt) {
                const unsigned short* ap =
                    (ks < 2)  ? (S0[mt] + ks * 32) :
                    (ks < 6)  ? (S1[mt] + (ks - 2) * 32) :
                    (ks < 10) ? (S2[mt] + (ks - 6) * 32) :
                    (ks < 12) ? (S3[mt] + (ks - 10) * 32) :
                    (ks < 16) ? (S4[mt] + (ks - 12) * 32) :
                                (S5[mt] + (ks - 16) * 32);
                bf8 a = *(const bf8*)ap;
#pragma unroll
                for (int nt = 0; nt < 2; ++nt)
                    acc[mt][nt] = __builtin_amdgcn_mfma_f32_16x16x32_bf16(
                        a, Breg[kl * 2 + nt], acc[mt][nt], 0, 0, 0);
            }
        }
    }
#pragma unroll
    for (int mt = 0; mt < 2; ++mt)
#pragma unroll
        for (int reg = 0; reg < 4; ++reg) {
            int r = rowbase + mt * 16 + quad * 4 + reg;
            if (r >= n) continue;
#pragma unroll
            for (int nt = 0; nt < 2; ++nt) {
                int cidx = ngrp * 32 + nt * 16 + lr;
                float ht = tanhf(acc[mt][nt][reg] + bh[cidx]);
                float z = Zf[(size_t)r * 64 + cidx];
                float h_old = H[(size_t)r * 64 + cidx];
                out[(size_t)r * 64 + cidx] = z * h_old + (1.f - z) * ht;
            }
        }
}

// ---------------- launch ----------------

static inline size_t rup(size_t x) { return (x + 63) & ~(size_t)63; }

extern "C" void kernel_launch(void* const* d_in, const int* in_sizes, int n_in,
                              void* d_out, int out_size, void* d_ws, size_t ws_size,
                              hipStream_t stream) {
    const float* X  = (const float*)d_in[0];
    const int*   EI = (const int*)d_in[1];
    const float* H  = (const float*)d_in[2];
    const float* Wz = (const float*)d_in[3];
    const float* bz = (const float*)d_in[4];
    const float* Wr = (const float*)d_in[5];
    const float* br = (const float*)d_in[6];
    const float* Wh = (const float*)d_in[7];
    const float* bh = (const float*)d_in[8];
    float* out = (float*)d_out;

    const int* row = EI;
    const int* col = EI + N_EDGES;

    char* ws = (char*)d_ws;
    size_t off = 0;
    auto carve = [&](size_t bytes) { void* p = ws + off; off += rup(bytes); return p; };

    int*   deg_out   = (int*)carve(N_NODES * 4);
    int*   deg_in    = (int*)carve(N_NODES * 4);
    int*   rowptr    = (int*)carve((N_NODES + 1) * 4);
    int*   cursor    = (int*)carve(N_NODES * 4);
    int*   blocksums = (int*)carve(64 * 4);
    float2* winv     = (float2*)carve(N_NODES * 8);
    int*   csr_src   = (int*)carve(N_EDGES * 4);
    float2* csr_w    = (float2*)carve(N_EDGES * 8);
    unsigned short* XH = (unsigned short*)carve((size_t)N_NODES * 128 * 2);
    unsigned short* P1 = (unsigned short*)carve((size_t)N_NODES * 256 * 2);
    unsigned short* P2 = (unsigned short*)carve((size_t)N_NODES * 256 * 2);
    unsigned short* HR = (unsigned short*)carve((size_t)N_NODES * 64 * 2);
    unsigned short* Q1 = (unsigned short*)carve((size_t)N_NODES * 128 * 2);
    unsigned short* Q2 = (unsigned short*)carve((size_t)N_NODES * 128 * 2);
    float* Zf          = (float*)carve((size_t)N_NODES * 64 * 4);
    unsigned short* Wzr_t = (unsigned short*)carve(128 * 640 * 2);
    unsigned short* Wh_t  = (unsigned short*)carve(64 * 640 * 2);

    hipMemsetAsync(deg_out, 0, rup(N_NODES * 4) + rup(N_NODES * 4), stream);
    count_deg<<<(N_EDGES + 255) / 256, 256, 0, stream>>>(row, col, deg_out, deg_in, N_EDGES);

    int nblk = (N_NODES + 1023) / 1024;
    scan_block<<<nblk, 1024, 0, stream>>>(deg_in, rowptr, blocksums, N_NODES);
    scan_sums<<<1, 64, 0, stream>>>(blocksums, nblk);
    scan_add<<<(N_NODES + 1 + 255) / 256, 256, 0, stream>>>(rowptr, blocksums, cursor,
                                                            deg_out, deg_in, winv, N_NODES, N_EDGES);

    build_csr<<<(N_EDGES + 255) / 256, 256, 0, stream>>>(row, col, winv, cursor,
                                                         csr_src, csr_w, N_EDGES);

    pack_weights<<<(128 * 640 + 64 * 640 + 255) / 256, 256, 0, stream>>>(Wz, Wr, Wh, Wzr_t, Wh_t);

    concat_xh<<<(N_NODES * C_DIM + 255) / 256, 256, 0, stream>>>(X, H, XH, N_NODES);

    // props on XH: 2 nodes/wave
    int blocks_p128 = (((N_NODES + 1) / 2) * 64 + 255) / 256;
    prop1_128<<<blocks_p128, 256, 0, stream>>>(XH, rowptr, csr_src, csr_w, P1, N_NODES);
    prop2_128<<<blocks_p128, 256, 0, stream>>>(P1, XH, rowptr, csr_src, csr_w, P2, N_NODES);

    // Z|R GEMM -> Zf, HR
    int gemm_blocks = (N_NODES + 63) / 64;
    gemm_zr_mfma<<<gemm_blocks, 256, 0, stream>>>(XH, P1, P2, Wzr_t, bz, br, H, Zf, HR, N_NODES);

    // props on HR: 4 nodes/wave
    int blocks_p64 = (((N_NODES + 3) / 4) * 64 + 255) / 256;
    prop1_64<<<blocks_p64, 256, 0, stream>>>(HR, rowptr, csr_src, csr_w, Q1, N_NODES);
    prop2_64<<<blocks_p64, 256, 0, stream>>>(Q1, HR, rowptr, csr_src, csr_w, Q2, N_NODES);

    // H~ GEMM + GRU mix -> out
    gemm_h_mfma<<<gemm_blocks, 256, 0, stream>>>(XH, P1, P2, HR, Q1, Q2,
                                                 Wh_t, bh, Zf, H, out, N_NODES);
}

// Round 6
// 407.679 us; speedup vs baseline: 1.0050x; 1.0050x over previous
//
#include <hip/hip_runtime.h>
#include <hip/hip_bf16.h>
#include <math.h>

#define N_NODES 50000
#define N_EDGES 500000
#define C_DIM 128

typedef __attribute__((ext_vector_type(8))) short bf8;
typedef __attribute__((ext_vector_type(4))) float f32x4;

__device__ __forceinline__ float bflo(unsigned u) { return __uint_as_float(u << 16); }
__device__ __forceinline__ float bfhi(unsigned u) { return __uint_as_float(u & 0xffff0000u); }
__device__ __forceinline__ unsigned short f2bfu(float f) {
    __hip_bfloat16 h = __float2bfloat16(f);
    unsigned short u;
    __builtin_memcpy(&u, &h, 2);
    return u;
}
__device__ __forceinline__ unsigned packbf(float a, float b) {
    return ((unsigned)f2bfu(b) << 16) | f2bfu(a);
}

// async global->LDS, 16B per lane; lds dest = wave-uniform base + lane*16
__device__ __forceinline__ void gload_lds16(const void* g, void* l) {
    __builtin_amdgcn_global_load_lds(
        (const __attribute__((address_space(1))) void*)g,
        (__attribute__((address_space(3))) void*)l, 16, 0, 0);
}

// ---------------- graph preprocessing ----------------

__global__ void count_deg(const int* __restrict__ row, const int* __restrict__ col,
                          int* __restrict__ dout, int* __restrict__ din, int e) {
    int i = blockIdx.x * blockDim.x + threadIdx.x;
    if (i >= e) return;
    atomicAdd(&dout[row[i]], 1);
    atomicAdd(&din[col[i]], 1);
}

__global__ void scan_block(const int* __restrict__ counts, int* __restrict__ excl,
                           int* __restrict__ blocksums, int n) {
    __shared__ int tmp[1024];
    int tid = threadIdx.x;
    int gid = blockIdx.x * 1024 + tid;
    int v = (gid < n) ? counts[gid] : 0;
    tmp[tid] = v;
    __syncthreads();
    for (int off = 1; off < 1024; off <<= 1) {
        int t = (tid >= off) ? tmp[tid - off] : 0;
        __syncthreads();
        tmp[tid] += t;
        __syncthreads();
    }
    int incl = tmp[tid];
    if (gid < n) excl[gid] = incl - v;
    if (tid == 1023) blocksums[blockIdx.x] = incl;
}

__global__ void scan_sums(int* __restrict__ blocksums, int nb) {
    __shared__ int tmp[64];
    int tid = threadIdx.x;
    int v = (tid < nb) ? blocksums[tid] : 0;
    tmp[tid] = v;
    __syncthreads();
    for (int off = 1; off < 64; off <<= 1) {
        int t = (tid >= off) ? tmp[tid - off] : 0;
        __syncthreads();
        tmp[tid] += t;
        __syncthreads();
    }
    if (tid < nb) blocksums[tid] = tmp[tid] - v;
}

__global__ void scan_add(int* __restrict__ rowptr, const int* __restrict__ blocksums,
                         int* __restrict__ cursor, const int* __restrict__ dout,
                         const int* __restrict__ din, float2* __restrict__ winv,
                         int n, int e_total) {
    int gid = blockIdx.x * blockDim.x + threadIdx.x;
    if (gid < n) {
        int v = rowptr[gid] + blocksums[gid >> 10];
        rowptr[gid] = v;
        cursor[gid] = v;
        winv[gid] = make_float2(1.0f / (float)dout[gid], 1.0f / (float)din[gid]);
    }
    if (gid == n) rowptr[n] = e_total;
}

__global__ void build_csr(const int* __restrict__ row, const int* __restrict__ col,
                          const float2* __restrict__ winv,
                          int* __restrict__ cursor, int* __restrict__ src,
                          float2* __restrict__ w, int e) {
    int i = blockIdx.x * blockDim.x + threadIdx.x;
    if (i >= e) return;
    int r = row[i], c = col[i];
    int pos = atomicAdd(&cursor[c], 1);
    src[pos] = r;
    w[pos] = winv[r];
}

// ---------------- weight packing (bf16, [n][640], interleaved k-order) ------
__device__ __forceinline__ float wraw(const float* W, int d, int kk, int k, int j) {
    return W[((d * 3 + kk) * 128 + k) * 64 + j];
}

__global__ void pack_weights(const float* __restrict__ Wz, const float* __restrict__ Wr,
                             const float* __restrict__ Wh,
                             unsigned short* __restrict__ Wzr_t,   // [128][640]
                             unsigned short* __restrict__ Wh_t) {  // [64][640]
    int i = blockIdx.x * blockDim.x + threadIdx.x;
    if (i < 128 * 640) {
        int k = i % 640;
        int nn = i / 640;
        const float* W = (nn < 64) ? Wz : Wr;
        int j = nn & 63;
        float v;
        if (k < 128) {
            v = wraw(W, 0, 0, k, j) + wraw(W, 1, 0, k, j);
        } else {
            int k2 = k - 128;
            int kk = (k2 >= 256) ? 2 : 1;
            int k3 = k2 & 255;
            int p = k3 >> 2, sub = k3 & 3;
            v = wraw(W, sub >> 1, kk, 2 * p + (sub & 1), j);
        }
        Wzr_t[i] = f2bfu(v);
    } else if (i < 128 * 640 + 64 * 640) {
        int i2 = i - 128 * 640;
        int k = i2 % 640;
        int j = i2 / 640;
        float v;
        if (k < 64) {
            v = wraw(Wh, 0, 0, k, j) + wraw(Wh, 1, 0, k, j);
        } else if (k < 320) {
            int k2 = k - 64;
            int kk = (k2 >= 128) ? 2 : 1;
            int k3 = k2 & 127;
            int p = k3 >> 2, sub = k3 & 3;
            v = wraw(Wh, sub >> 1, kk, 2 * p + (sub & 1), j);
        } else if (k < 384) {
            int rr = k - 320;
            v = wraw(Wh, 0, 0, 64 + rr, j) + wraw(Wh, 1, 0, 64 + rr, j);
        } else {
            int k2 = k - 384;
            int kk = (k2 >= 128) ? 2 : 1;
            int k3 = k2 & 127;
            int p = k3 >> 2, sub = k3 & 3;
            v = wraw(Wh, sub >> 1, kk, 64 + 2 * p + (sub & 1), j);
        }
        Wh_t[i2] = f2bfu(v);
    }
}

// ---------------- concat ----------------

__global__ void concat_xh(const float* __restrict__ X, const float* __restrict__ H,
                          unsigned short* __restrict__ XH, int n) {
    int i = blockIdx.x * blockDim.x + threadIdx.x;
    if (i >= n * C_DIM) return;
    int r = i >> 7, c = i & 127;
    float v = (c < 64) ? X[r * 64 + c] : H[r * 64 + (c - 64)];
    XH[i] = f2bfu(v);
}

// ---------------- diffusion props ----------------
// P layout [n][256]: pair p (0..63): cols 4p..4p+3 = {o(2p), o(2p+1), i(2p), i(2p+1)}
// Q layout [n][128]: same with 32 pairs.

__global__ void prop1_128(const unsigned short* __restrict__ S,
                          const int* __restrict__ rowptr, const int* __restrict__ src,
                          const float2* __restrict__ w,
                          unsigned short* __restrict__ P1, int n) {
    int tid = blockIdx.x * blockDim.x + threadIdx.x;
    int lane = tid & 63;
    int node = ((tid >> 6) << 1) + (lane >> 5);
    int p = lane & 31;
    if (node >= n) return;
    int beg = rowptr[node], end = rowptr[node + 1];
    float ao0 = 0.f, ao1 = 0.f, ao2 = 0.f, ao3 = 0.f;
    float ai0 = 0.f, ai1 = 0.f, ai2 = 0.f, ai3 = 0.f;
    int j = beg;
#define P1STEP(s_, w_) {                                                     \
        uint2 u = *(const uint2*)(S + (size_t)(s_) * 128 + 4 * p);           \
        float c0 = bflo(u.x), c1 = bfhi(u.x), c2 = bflo(u.y), c3 = bfhi(u.y);\
        ao0 = fmaf(w_.x, c0, ao0); ao1 = fmaf(w_.x, c1, ao1);                \
        ao2 = fmaf(w_.x, c2, ao2); ao3 = fmaf(w_.x, c3, ao3);                \
        ai0 = fmaf(w_.y, c0, ai0); ai1 = fmaf(w_.y, c1, ai1);                \
        ai2 = fmaf(w_.y, c2, ai2); ai3 = fmaf(w_.y, c3, ai3); }
    for (; j + 4 <= end; j += 4) {
        int s0 = src[j], s1 = src[j + 1], s2 = src[j + 2], s3 = src[j + 3];
        float2 w0 = w[j], w1 = w[j + 1], w2 = w[j + 2], w3 = w[j + 3];
        P1STEP(s0, w0); P1STEP(s1, w1); P1STEP(s2, w2); P1STEP(s3, w3);
    }
    for (; j < end; ++j) {
        int s = src[j]; float2 wv = w[j];
        P1STEP(s, wv);
    }
#undef P1STEP
    uint4 o;
    o.x = packbf(ao0, ao1); o.y = packbf(ai0, ai1);
    o.z = packbf(ao2, ao3); o.w = packbf(ai2, ai3);
    *(uint4*)(P1 + (size_t)node * 256 + 8 * p) = o;
}

__global__ void prop2_128(const unsigned short* __restrict__ P1,
                          const unsigned short* __restrict__ Xc,
                          const int* __restrict__ rowptr, const int* __restrict__ src,
                          const float2* __restrict__ w,
                          unsigned short* __restrict__ P2, int n) {
    int tid = blockIdx.x * blockDim.x + threadIdx.x;
    int lane = tid & 63;
    int node = ((tid >> 6) << 1) + (lane >> 5);
    int p = lane & 31;
    if (node >= n) return;
    int beg = rowptr[node], end = rowptr[node + 1];
    float oa = 0.f, ob = 0.f, oc = 0.f, od = 0.f;
    float ia = 0.f, ib = 0.f, ic = 0.f, id = 0.f;
    int j = beg;
#define P2STEP(s_, w_) {                                                     \
        uint4 v = *(const uint4*)(P1 + (size_t)(s_) * 256 + 8 * p);          \
        oa = fmaf(w_.x, bflo(v.x), oa); ob = fmaf(w_.x, bfhi(v.x), ob);      \
        ia = fmaf(w_.y, bflo(v.y), ia); ib = fmaf(w_.y, bfhi(v.y), ib);      \
        oc = fmaf(w_.x, bflo(v.z), oc); od = fmaf(w_.x, bfhi(v.z), od);      \
        ic = fmaf(w_.y, bflo(v.w), ic); id = fmaf(w_.y, bfhi(v.w), id); }
    for (; j + 4 <= end; j += 4) {
        int s0 = src[j], s1 = src[j + 1], s2 = src[j + 2], s3 = src[j + 3];
        float2 w0 = w[j], w1 = w[j + 1], w2 = w[j + 2], w3 = w[j + 3];
        P2STEP(s0, w0); P2STEP(s1, w1); P2STEP(s2, w2); P2STEP(s3, w3);
    }
    for (; j < end; ++j) {
        int s = src[j]; float2 wv = w[j];
        P2STEP(s, wv);
    }
#undef P2STEP
    uint2 ux = *(const uint2*)(Xc + (size_t)node * 128 + 4 * p);
    float xa = bflo(ux.x), xb = bfhi(ux.x), xc = bflo(ux.y), xd = bfhi(ux.y);
    uint4 o;
    o.x = packbf(2.f * oa - xa, 2.f * ob - xb);
    o.y = packbf(2.f * ia - xa, 2.f * ib - xb);
    o.z = packbf(2.f * oc - xc, 2.f * od - xd);
    o.w = packbf(2.f * ic - xc, 2.f * id - xd);
    *(uint4*)(P2 + (size_t)node * 256 + 8 * p) = o;
}

__global__ void prop1_64(const unsigned short* __restrict__ HR,
                         const int* __restrict__ rowptr, const int* __restrict__ src,
                         const float2* __restrict__ w,
                         unsigned short* __restrict__ Q1, int n) {
    int tid = blockIdx.x * blockDim.x + threadIdx.x;
    int lane = tid & 63;
    int node = ((tid >> 6) << 2) + (lane >> 4);
    int p = lane & 15;
    if (node >= n) return;
    int beg = rowptr[node], end = rowptr[node + 1];
    float ao0 = 0.f, ao1 = 0.f, ao2 = 0.f, ao3 = 0.f;
    float ai0 = 0.f, ai1 = 0.f, ai2 = 0.f, ai3 = 0.f;
    int j = beg;
#define Q1STEP(s_, w_) {                                                     \
        uint2 u = *(const uint2*)(HR + (size_t)(s_) * 64 + 4 * p);           \
        float c0 = bflo(u.x), c1 = bfhi(u.x), c2 = bflo(u.y), c3 = bfhi(u.y);\
        ao0 = fmaf(w_.x, c0, ao0); ao1 = fmaf(w_.x, c1, ao1);                \
        ao2 = fmaf(w_.x, c2, ao2); ao3 = fmaf(w_.x, c3, ao3);                \
        ai0 = fmaf(w_.y, c0, ai0); ai1 = fmaf(w_.y, c1, ai1);                \
        ai2 = fmaf(w_.y, c2, ai2); ai3 = fmaf(w_.y, c3, ai3); }
    for (; j + 4 <= end; j += 4) {
        int s0 = src[j], s1 = src[j + 1], s2 = src[j + 2], s3 = src[j + 3];
        float2 w0 = w[j], w1 = w[j + 1], w2 = w[j + 2], w3 = w[j + 3];
        Q1STEP(s0, w0); Q1STEP(s1, w1); Q1STEP(s2, w2); Q1STEP(s3, w3);
    }
    for (; j < end; ++j) {
        int s = src[j]; float2 wv = w[j];
        Q1STEP(s, wv);
    }
#undef Q1STEP
    uint4 o;
    o.x = packbf(ao0, ao1); o.y = packbf(ai0, ai1);
    o.z = packbf(ao2, ao3); o.w = packbf(ai2, ai3);
    *(uint4*)(Q1 + (size_t)node * 128 + 8 * p) = o;
}

__global__ void prop2_64(const unsigned short* __restrict__ Q1,
                         const unsigned short* __restrict__ HR,
                         const int* __restrict__ rowptr, const int* __restrict__ src,
                         const float2* __restrict__ w,
                         unsigned short* __restrict__ Q2, int n) {
    int tid = blockIdx.x * blockDim.x + threadIdx.x;
    int lane = tid & 63;
    int node = ((tid >> 6) << 2) + (lane >> 4);
    int p = lane & 15;
    if (node >= n) return;
    int beg = rowptr[node], end = rowptr[node + 1];
    float oa = 0.f, ob = 0.f, oc = 0.f, od = 0.f;
    float ia = 0.f, ib = 0.f, ic = 0.f, id = 0.f;
    int j = beg;
#define Q2STEP(s_, w_) {                                                     \
        uint4 v = *(const uint4*)(Q1 + (size_t)(s_) * 128 + 8 * p);          \
        oa = fmaf(w_.x, bflo(v.x), oa); ob = fmaf(w_.x, bfhi(v.x), ob);      \
        ia = fmaf(w_.y, bflo(v.y), ia); ib = fmaf(w_.y, bfhi(v.y), ib);      \
        oc = fmaf(w_.x, bflo(v.z), oc); od = fmaf(w_.x, bfhi(v.z), od);      \
        ic = fmaf(w_.y, bflo(v.w), ic); id = fmaf(w_.y, bfhi(v.w), id); }
    for (; j + 4 <= end; j += 4) {
        int s0 = src[j], s1 = src[j + 1], s2 = src[j + 2], s3 = src[j + 3];
        float2 w0 = w[j], w1 = w[j + 1], w2 = w[j + 2], w3 = w[j + 3];
        Q2STEP(s0, w0); Q2STEP(s1, w1); Q2STEP(s2, w2); Q2STEP(s3, w3);
    }
    for (; j < end; ++j) {
        int s = src[j]; float2 wv = w[j];
        Q2STEP(s, wv);
    }
#undef Q2STEP
    uint2 ux = *(const uint2*)(HR + (size_t)node * 64 + 4 * p);
    float xa = bflo(ux.x), xb = bfhi(ux.x), xc = bflo(ux.y), xd = bfhi(ux.y);
    uint4 o;
    o.x = packbf(2.f * oa - xa, 2.f * ob - xb);
    o.y = packbf(2.f * ia - xa, 2.f * ib - xb);
    o.z = packbf(2.f * oc - xc, 2.f * od - xd);
    o.w = packbf(2.f * ic - xc, 2.f * id - xd);
    *(uint4*)(Q2 + (size_t)node * 128 + 8 * p) = o;
}

// ---------------- MFMA GEMMs: async LDS double-buffer (m97 pattern) ---------
// mfma_f32_16x16x32_bf16: A[m=lane&15][k=quad*8+j]; B[k=quad*8+j][n=lane&15];
// C/D: col=lane&15, row=quad*4+reg.
// LDS layout (q-major, 16B lane-contiguous as global_load_lds requires):
//   A: (q,row)  -> q*64*8  + row*8 shorts  (q = 8-elem k-subgroup, 8 per BK=64)
//   B: (q,col)  -> q*NC*8  + col*8 shorts
// ds_read_b128 lane stride = 16B -> 2-way bank aliasing (free, m136).

// ZR: block 64 rows x 128 cols, 4 waves = (mh, nh) each 32r x 64c. 10 chunks BK=64.
__global__ __launch_bounds__(256) void gemm_zr_mfma(
    const unsigned short* __restrict__ XH, const unsigned short* __restrict__ P1,
    const unsigned short* __restrict__ P2,
    const unsigned short* __restrict__ Wt, const float* __restrict__ bz,
    const float* __restrict__ br, const float* __restrict__ H,
    float* __restrict__ Zf, unsigned short* __restrict__ HR, int n) {
    __shared__ unsigned short Al[2][8 * 64 * 8];    // 8 KB per buffer
    __shared__ unsigned short Bl[2][8 * 128 * 8];   // 16 KB per buffer
    int tid = threadIdx.x;
    int lane = tid & 63;
    int wid = tid >> 6;
    int mh = wid & 1, nh = wid >> 1;
    int rowbase = blockIdx.x * 64;
    int lr = lane & 15, quad = lane >> 4;

    // A-chunk source table: c0-1 XH, c2-5 P1, c6-9 P2
    auto stage = [&](int c, int buf) {
        const unsigned short* T;
        int str, toff;
        if (c < 2)      { T = XH; str = 128; toff = c * 64; }
        else if (c < 6) { T = P1; str = 256; toff = (c - 2) * 64; }
        else            { T = P2; str = 256; toff = (c - 6) * 64; }
        int kb = c * 64;
        int grow = rowbase + lane; if (grow >= n) grow = n - 1;
#pragma unroll
        for (int j = 0; j < 6; ++j) {
            int idx = wid * 6 + j;
            if (idx < 8) {
                int q = idx;
                gload_lds16(T + (size_t)grow * str + toff + q * 8,
                            &Al[buf][q * 512]);
            } else {
                int t = idx - 8;
                int q = t >> 1, h = t & 1;
                int col = h * 64 + lane;
                gload_lds16(Wt + (size_t)col * 640 + kb + q * 8,
                            &Bl[buf][q * 1024 + h * 512]);
            }
        }
    };

    f32x4 zero = {0.f, 0.f, 0.f, 0.f};
    f32x4 acc[2][4];
#pragma unroll
    for (int a = 0; a < 2; ++a)
#pragma unroll
        for (int b = 0; b < 4; ++b) acc[a][b] = zero;

    stage(0, 0);
    for (int c = 0; c < 10; ++c) {
        int buf = c & 1;
        __syncthreads();                  // drains this wave's global_load_lds + prior ds_reads
        if (c < 9) stage(c + 1, buf ^ 1);
#pragma unroll
        for (int s = 0; s < 2; ++s) {
            int q = s * 4 + quad;
            bf8 af[2], bfr[4];
#pragma unroll
            for (int mt = 0; mt < 2; ++mt)
                af[mt] = *(const bf8*)&Al[buf][q * 512 + (mh * 32 + mt * 16 + lr) * 8];
#pragma unroll
            for (int nt = 0; nt < 4; ++nt)
                bfr[nt] = *(const bf8*)&Bl[buf][q * 1024 + (nh * 64 + nt * 16 + lr) * 8];
#pragma unroll
            for (int mt = 0; mt < 2; ++mt)
#pragma unroll
                for (int nt = 0; nt < 4; ++nt)
                    acc[mt][nt] = __builtin_amdgcn_mfma_f32_16x16x32_bf16(
                        af[mt], bfr[nt], acc[mt][nt], 0, 0, 0);
        }
    }
#pragma unroll
    for (int mt = 0; mt < 2; ++mt)
#pragma unroll
        for (int reg = 0; reg < 4; ++reg) {
            int r = rowbase + mh * 32 + mt * 16 + quad * 4 + reg;
            if (r >= n) continue;
#pragma unroll
            for (int nt = 0; nt < 4; ++nt) {
                int cidx = nh * 64 + nt * 16 + lr;
                float bias = (cidx < 64) ? bz[cidx] : br[cidx - 64];
                float v = acc[mt][nt][reg] + bias;
                float s = 1.f / (1.f + expf(-v));
                if (cidx < 64) {
                    Zf[(size_t)r * 64 + cidx] = s;
                } else {
                    int c2 = cidx - 64;
                    HR[(size_t)r * 64 + c2] = f2bfu(H[(size_t)r * 64 + c2] * s);
                }
            }
        }
}

// H~: block 64 rows x 64 cols, 4 waves = (mh, nh) each 32r x 32c. 10 chunks BK=64.
__global__ __launch_bounds__(256) void gemm_h_mfma(
    const unsigned short* __restrict__ XH, const unsigned short* __restrict__ P1,
    const unsigned short* __restrict__ P2, const unsigned short* __restrict__ HR,
    const unsigned short* __restrict__ Q1, const unsigned short* __restrict__ Q2,
    const unsigned short* __restrict__ Wt, const float* __restrict__ bh,
    const float* __restrict__ Zf, const float* __restrict__ H,
    float* __restrict__ out, int n) {
    __shared__ unsigned short Al[2][8 * 64 * 8];   // 8 KB per buffer
    __shared__ unsigned short Bl[2][8 * 64 * 8];   // 8 KB per buffer
    int tid = threadIdx.x;
    int lane = tid & 63;
    int wid = tid >> 6;
    int mh = wid & 1, nh = wid >> 1;
    int rowbase = blockIdx.x * 64;
    int lr = lane & 15, quad = lane >> 4;

    // A-chunk table: c0 XH, c1-2 P1, c3-4 P2, c5 HR, c6-7 Q1, c8-9 Q2
    auto stage = [&](int c, int buf) {
        const unsigned short* T;
        int str, toff;
        if (c == 0)      { T = XH; str = 128; toff = 0; }
        else if (c < 3)  { T = P1; str = 256; toff = (c - 1) * 64; }
        else if (c < 5)  { T = P2; str = 256; toff = (c - 3) * 64; }
        else if (c == 5) { T = HR; str = 64;  toff = 0; }
        else if (c < 8)  { T = Q1; str = 128; toff = (c - 6) * 64; }
        else             { T = Q2; str = 128; toff = (c - 8) * 64; }
        int kb = c * 64;
        int grow = rowbase + lane; if (grow >= n) grow = n - 1;
#pragma unroll
        for (int j = 0; j < 4; ++j) {
            int idx = wid * 4 + j;
            if (idx < 8) {
                int q = idx;
                gload_lds16(T + (size_t)grow * str + toff + q * 8,
                            &Al[buf][q * 512]);
            } else {
                int q = idx - 8;
                gload_lds16(Wt + (size_t)lane * 640 + kb + q * 8,
                            &Bl[buf][q * 512]);
            }
        }
    };

    f32x4 zero = {0.f, 0.f, 0.f, 0.f};
    f32x4 acc[2][2];
#pragma unroll
    for (int a = 0; a < 2; ++a)
#pragma unroll
        for (int b = 0; b < 2; ++b) acc[a][b] = zero;

    stage(0, 0);
    for (int c = 0; c < 10; ++c) {
        int buf = c & 1;
        __syncthreads();
        if (c < 9) stage(c + 1, buf ^ 1);
#pragma unroll
        for (int s = 0; s < 2; ++s) {
            int q = s * 4 + quad;
            bf8 af[2], bfr[2];
#pragma unroll
            for (int mt = 0; mt < 2; ++mt)
                af[mt] = *(const bf8*)&Al[buf][q * 512 + (mh * 32 + mt * 16 + lr) * 8];
#pragma unroll
            for (int nt = 0; nt < 2; ++nt)
                bfr[nt] = *(const bf8*)&Bl[buf][q * 512 + (nh * 32 + nt * 16 + lr) * 8];
#pragma unroll
            for (int mt = 0; mt < 2; ++mt)
#pragma unroll
                for (int nt = 0; nt < 2; ++nt)
                    acc[mt][nt] = __builtin_amdgcn_mfma_f32_16x16x32_bf16(
                        af[mt], bfr[nt], acc[mt][nt], 0, 0, 0);
        }
    }
#pragma unroll
    for (int mt = 0; mt < 2; ++mt)
#pragma unroll
        for (int reg = 0; reg < 4; ++reg) {
            int r = rowbase + mh * 32 + mt * 16 + quad * 4 + reg;
            if (r >= n) continue;
#pragma unroll
            for (int nt = 0; nt < 2; ++nt) {
                int cidx = nh * 32 + nt * 16 + lr;
                float ht = tanhf(acc[mt][nt][reg] + bh[cidx]);
                float z = Zf[(size_t)r * 64 + cidx];
                float h_old = H[(size_t)r * 64 + cidx];
                out[(size_t)r * 64 + cidx] = z * h_old + (1.f - z) * ht;
            }
        }
}

// ---------------- launch ----------------

static inline size_t rup(size_t x) { return (x + 63) & ~(size_t)63; }

extern "C" void kernel_launch(void* const* d_in, const int* in_sizes, int n_in,
                              void* d_out, int out_size, void* d_ws, size_t ws_size,
                              hipStream_t stream) {
    const float* X  = (const float*)d_in[0];
    const int*   EI = (const int*)d_in[1];
    const float* H  = (const float*)d_in[2];
    const float* Wz = (const float*)d_in[3];
    const float* bz = (const float*)d_in[4];
    const float* Wr = (const float*)d_in[5];
    const float* br = (const float*)d_in[6];
    const float* Wh = (const float*)d_in[7];
    const float* bh = (const float*)d_in[8];
    float* out = (float*)d_out;

    const int* row = EI;
    const int* col = EI + N_EDGES;

    char* ws = (char*)d_ws;
    size_t off = 0;
    auto carve = [&](size_t bytes) { void* p = ws + off; off += rup(bytes); return p; };

    int*   deg_out   = (int*)carve(N_NODES * 4);
    int*   deg_in    = (int*)carve(N_NODES * 4);
    int*   rowptr    = (int*)carve((N_NODES + 1) * 4);
    int*   cursor    = (int*)carve(N_NODES * 4);
    int*   blocksums = (int*)carve(64 * 4);
    float2* winv     = (float2*)carve(N_NODES * 8);
    int*   csr_src   = (int*)carve(N_EDGES * 4);
    float2* csr_w    = (float2*)carve(N_EDGES * 8);
    unsigned short* XH = (unsigned short*)carve((size_t)N_NODES * 128 * 2);
    unsigned short* P1 = (unsigned short*)carve((size_t)N_NODES * 256 * 2);
    unsigned short* P2 = (unsigned short*)carve((size_t)N_NODES * 256 * 2);
    unsigned short* HR = (unsigned short*)carve((size_t)N_NODES * 64 * 2);
    unsigned short* Q1 = (unsigned short*)carve((size_t)N_NODES * 128 * 2);
    unsigned short* Q2 = (unsigned short*)carve((size_t)N_NODES * 128 * 2);
    float* Zf          = (float*)carve((size_t)N_NODES * 64 * 4);
    unsigned short* Wzr_t = (unsigned short*)carve(128 * 640 * 2);
    unsigned short* Wh_t  = (unsigned short*)carve(64 * 640 * 2);

    hipMemsetAsync(deg_out, 0, rup(N_NODES * 4) + rup(N_NODES * 4), stream);
    count_deg<<<(N_EDGES + 255) / 256, 256, 0, stream>>>(row, col, deg_out, deg_in, N_EDGES);

    int nblk = (N_NODES + 1023) / 1024;
    scan_block<<<nblk, 1024, 0, stream>>>(deg_in, rowptr, blocksums, N_NODES);
    scan_sums<<<1, 64, 0, stream>>>(blocksums, nblk);
    scan_add<<<(N_NODES + 1 + 255) / 256, 256, 0, stream>>>(rowptr, blocksums, cursor,
                                                            deg_out, deg_in, winv, N_NODES, N_EDGES);

    build_csr<<<(N_EDGES + 255) / 256, 256, 0, stream>>>(row, col, winv, cursor,
                                                         csr_src, csr_w, N_EDGES);

    pack_weights<<<(128 * 640 + 64 * 640 + 255) / 256, 256, 0, stream>>>(Wz, Wr, Wh, Wzr_t, Wh_t);

    concat_xh<<<(N_NODES * C_DIM + 255) / 256, 256, 0, stream>>>(X, H, XH, N_NODES);

    // props on XH: 2 nodes/wave
    int blocks_p128 = (((N_NODES + 1) / 2) * 64 + 255) / 256;
    prop1_128<<<blocks_p128, 256, 0, stream>>>(XH, rowptr, csr_src, csr_w, P1, N_NODES);
    prop2_128<<<blocks_p128, 256, 0, stream>>>(P1, XH, rowptr, csr_src, csr_w, P2, N_NODES);

    // Z|R GEMM -> Zf, HR
    int gemm_blocks = (N_NODES + 63) / 64;
    gemm_zr_mfma<<<gemm_blocks, 256, 0, stream>>>(XH, P1, P2, Wzr_t, bz, br, H, Zf, HR, N_NODES);

    // props on HR: 4 nodes/wave
    int blocks_p64 = (((N_NODES + 3) / 4) * 64 + 255) / 256;
    prop1_64<<<blocks_p64, 256, 0, stream>>>(HR, rowptr, csr_src, csr_w, Q1, N_NODES);
    prop2_64<<<blocks_p64, 256, 0, stream>>>(Q1, HR, rowptr, csr_src, csr_w, Q2, N_NODES);

    // H~ GEMM + GRU mix -> out
    gemm_h_mfma<<<gemm_blocks, 256, 0, stream>>>(XH, P1, P2, HR, Q1, Q2,
                                                 Wh_t, bh, Zf, H, out, N_NODES);
}

// Round 7
// 369.366 us; speedup vs baseline: 1.1093x; 1.1037x over previous
//
#include <hip/hip_runtime.h>
#include <hip/hip_bf16.h>
#include <math.h>

#define N_NODES 50000
#define N_EDGES 500000
#define C_DIM 128
#define N_TILES 3125   // 50000/16 exact

typedef __attribute__((ext_vector_type(8))) short bf8;
typedef __attribute__((ext_vector_type(4))) float f32x4;

__device__ __forceinline__ float bflo(unsigned u) { return __uint_as_float(u << 16); }
__device__ __forceinline__ float bfhi(unsigned u) { return __uint_as_float(u & 0xffff0000u); }
__device__ __forceinline__ unsigned short f2bfu(float f) {
    __hip_bfloat16 h = __float2bfloat16(f);
    unsigned short u;
    __builtin_memcpy(&u, &h, 2);
    return u;
}
__device__ __forceinline__ unsigned packbf(float a, float b) {
    return ((unsigned)f2bfu(b) << 16) | f2bfu(a);
}

// ---------------- graph preprocessing ----------------

__global__ void count_deg(const int* __restrict__ row, const int* __restrict__ col,
                          int* __restrict__ dout, int* __restrict__ din, int e) {
    int i = blockIdx.x * blockDim.x + threadIdx.x;
    if (i >= e) return;
    atomicAdd(&dout[row[i]], 1);
    atomicAdd(&din[col[i]], 1);
}

__global__ void scan_block(const int* __restrict__ counts, int* __restrict__ excl,
                           int* __restrict__ blocksums, int n) {
    __shared__ int tmp[1024];
    int tid = threadIdx.x;
    int gid = blockIdx.x * 1024 + tid;
    int v = (gid < n) ? counts[gid] : 0;
    tmp[tid] = v;
    __syncthreads();
    for (int off = 1; off < 1024; off <<= 1) {
        int t = (tid >= off) ? tmp[tid - off] : 0;
        __syncthreads();
        tmp[tid] += t;
        __syncthreads();
    }
    int incl = tmp[tid];
    if (gid < n) excl[gid] = incl - v;
    if (tid == 1023) blocksums[blockIdx.x] = incl;
}

__global__ void scan_sums(int* __restrict__ blocksums, int nb) {
    __shared__ int tmp[64];
    int tid = threadIdx.x;
    int v = (tid < nb) ? blocksums[tid] : 0;
    tmp[tid] = v;
    __syncthreads();
    for (int off = 1; off < 64; off <<= 1) {
        int t = (tid >= off) ? tmp[tid - off] : 0;
        __syncthreads();
        tmp[tid] += t;
        __syncthreads();
    }
    if (tid < nb) blocksums[tid] = tmp[tid] - v;
}

__global__ void scan_add(int* __restrict__ rowptr, const int* __restrict__ blocksums,
                         int* __restrict__ cursor, const int* __restrict__ dout,
                         const int* __restrict__ din, float2* __restrict__ winv,
                         int n, int e_total) {
    int gid = blockIdx.x * blockDim.x + threadIdx.x;
    if (gid < n) {
        int v = rowptr[gid] + blocksums[gid >> 10];
        rowptr[gid] = v;
        cursor[gid] = v;
        winv[gid] = make_float2(1.0f / (float)dout[gid], 1.0f / (float)din[gid]);
    }
    if (gid == n) rowptr[n] = e_total;
}

__global__ void build_csr(const int* __restrict__ row, const int* __restrict__ col,
                          const float2* __restrict__ winv,
                          int* __restrict__ cursor, int* __restrict__ src,
                          float2* __restrict__ w, int e) {
    int i = blockIdx.x * blockDim.x + threadIdx.x;
    if (i >= e) return;
    int r = row[i], c = col[i];
    int pos = atomicAdd(&cursor[c], 1);
    src[pos] = r;
    w[pos] = winv[r];
}

// ---------------- weight packing: MFMA fragment order ----------------
// Wzr_f[ks=20][ntile=8][lane=64][8]; Wh_f[ks=20][ntile=4][lane=64][8]
// B-frag(ks,ntile): value at k = ks*32 + (lane>>4)*8 + j, n = ntile*16 + (lane&15)
// with the established logical k-orders (verified rounds 3-6).
__device__ __forceinline__ float wraw(const float* W, int d, int kk, int k, int j) {
    return W[((d * 3 + kk) * 128 + k) * 64 + j];
}

__device__ __forceinline__ float zr_val(const float* Wz, const float* Wr, int k, int nn) {
    const float* W = (nn < 64) ? Wz : Wr;
    int j = nn & 63;
    if (k < 128) return wraw(W, 0, 0, k, j) + wraw(W, 1, 0, k, j);
    int k2 = k - 128;
    int kk = (k2 >= 256) ? 2 : 1;
    int k3 = k2 & 255;
    int p = k3 >> 2, sub = k3 & 3;
    return wraw(W, sub >> 1, kk, 2 * p + (sub & 1), j);
}

__device__ __forceinline__ float h_val(const float* Wh, int k, int j) {
    if (k < 64) return wraw(Wh, 0, 0, k, j) + wraw(Wh, 1, 0, k, j);
    if (k < 320) {
        int k2 = k - 64;
        int kk = (k2 >= 128) ? 2 : 1;
        int k3 = k2 & 127;
        int p = k3 >> 2, sub = k3 & 3;
        return wraw(Wh, sub >> 1, kk, 2 * p + (sub & 1), j);
    }
    if (k < 384) return wraw(Wh, 0, 0, 64 + (k - 320), j) + wraw(Wh, 1, 0, 64 + (k - 320), j);
    int k2 = k - 384;
    int kk = (k2 >= 128) ? 2 : 1;
    int k3 = k2 & 127;
    int p = k3 >> 2, sub = k3 & 3;
    return wraw(Wh, sub >> 1, kk, 64 + 2 * p + (sub & 1), j);
}

__global__ void pack_weights(const float* __restrict__ Wz, const float* __restrict__ Wr,
                             const float* __restrict__ Wh,
                             unsigned short* __restrict__ Wzrf,   // 20*8*64*8
                             unsigned short* __restrict__ Whf) {  // 20*4*64*8
    int i = blockIdx.x * blockDim.x + threadIdx.x;
    if (i < 20 * 8 * 64 * 8) {
        int j = i & 7, lane = (i >> 3) & 63, nt = (i >> 9) & 7, ks = i >> 12;
        int k = ks * 32 + (lane >> 4) * 8 + j;
        int nn = nt * 16 + (lane & 15);
        Wzrf[i] = f2bfu(zr_val(Wz, Wr, k, nn));
    } else if (i < 20 * 8 * 64 * 8 + 20 * 4 * 64 * 8) {
        int i2 = i - 20 * 8 * 64 * 8;
        int j = i2 & 7, lane = (i2 >> 3) & 63, nt = (i2 >> 9) & 3, ks = i2 >> 11;
        int k = ks * 32 + (lane >> 4) * 8 + j;
        int nn = nt * 16 + (lane & 15);
        Whf[i2] = f2bfu(h_val(Wh, k, nn));
    }
}

// ---------------- concat: XH row-major + fragment-packed ----------------
// packed T[tile][ck][lane][8]: 16B unit (ck,quad,lr) = cols ck*32+quad*8 .. +7 of row tile*16+lr

__global__ void concat_xh(const float* __restrict__ X, const float* __restrict__ H,
                          unsigned short* __restrict__ XH, unsigned short* __restrict__ XHp,
                          int n) {
    int t = blockIdx.x * blockDim.x + threadIdx.x;
    if (t >= n * 16) return;
    int node = t >> 4, p = t & 15;
    const float* src = (p < 8) ? (X + (size_t)node * 64 + 8 * p)
                               : (H + (size_t)node * 64 + 8 * (p - 8));
    float4 v0 = *(const float4*)src;
    float4 v1 = *(const float4*)(src + 4);
    uint4 o;
    o.x = packbf(v0.x, v0.y); o.y = packbf(v0.z, v0.w);
    o.z = packbf(v1.x, v1.y); o.w = packbf(v1.z, v1.w);
    *(uint4*)(XH + (size_t)node * 128 + 8 * p) = o;
    int tile = node >> 4, lr = node & 15, ck = p >> 2, q = p & 3;
    *(uint4*)(XHp + (((size_t)tile * 4 + ck) * 64 + q * 16 + lr) * 8) = o;
}

// ---------------- diffusion props ----------------
// row-major P/Q layouts as before (gather-friendly); packed copies for GEMM A.

__global__ void prop1_128(const unsigned short* __restrict__ S,
                          const int* __restrict__ rowptr, const int* __restrict__ src,
                          const float2* __restrict__ w,
                          unsigned short* __restrict__ P1, unsigned short* __restrict__ P1p,
                          int n) {
    int tid = blockIdx.x * blockDim.x + threadIdx.x;
    int lane = tid & 63;
    int node = ((tid >> 6) << 1) + (lane >> 5);
    int p = lane & 31;
    if (node >= n) return;
    int beg = rowptr[node], end = rowptr[node + 1];
    float ao0 = 0.f, ao1 = 0.f, ao2 = 0.f, ao3 = 0.f;
    float ai0 = 0.f, ai1 = 0.f, ai2 = 0.f, ai3 = 0.f;
    int j = beg;
#define P1STEP(s_, w_) {                                                     \
        uint2 u = *(const uint2*)(S + (size_t)(s_) * 128 + 4 * p);           \
        float c0 = bflo(u.x), c1 = bfhi(u.x), c2 = bflo(u.y), c3 = bfhi(u.y);\
        ao0 = fmaf(w_.x, c0, ao0); ao1 = fmaf(w_.x, c1, ao1);                \
        ao2 = fmaf(w_.x, c2, ao2); ao3 = fmaf(w_.x, c3, ao3);                \
        ai0 = fmaf(w_.y, c0, ai0); ai1 = fmaf(w_.y, c1, ai1);                \
        ai2 = fmaf(w_.y, c2, ai2); ai3 = fmaf(w_.y, c3, ai3); }
    for (; j + 4 <= end; j += 4) {
        int s0 = src[j], s1 = src[j + 1], s2 = src[j + 2], s3 = src[j + 3];
        float2 w0 = w[j], w1 = w[j + 1], w2 = w[j + 2], w3 = w[j + 3];
        P1STEP(s0, w0); P1STEP(s1, w1); P1STEP(s2, w2); P1STEP(s3, w3);
    }
    for (; j < end; ++j) {
        int s = src[j]; float2 wv = w[j];
        P1STEP(s, wv);
    }
#undef P1STEP
    uint4 o;
    o.x = packbf(ao0, ao1); o.y = packbf(ai0, ai1);
    o.z = packbf(ao2, ao3); o.w = packbf(ai2, ai3);
    *(uint4*)(P1 + (size_t)node * 256 + 8 * p) = o;
    int tile = node >> 4, lr = node & 15, ck = p >> 2, q = p & 3;
    *(uint4*)(P1p + (((size_t)tile * 8 + ck) * 64 + q * 16 + lr) * 8) = o;
}

__global__ void prop2_128(const unsigned short* __restrict__ P1,
                          const unsigned short* __restrict__ Xc,
                          const int* __restrict__ rowptr, const int* __restrict__ src,
                          const float2* __restrict__ w,
                          unsigned short* __restrict__ P2p, int n) {
    int tid = blockIdx.x * blockDim.x + threadIdx.x;
    int lane = tid & 63;
    int node = ((tid >> 6) << 1) + (lane >> 5);
    int p = lane & 31;
    if (node >= n) return;
    int beg = rowptr[node], end = rowptr[node + 1];
    float oa = 0.f, ob = 0.f, oc = 0.f, od = 0.f;
    float ia = 0.f, ib = 0.f, ic = 0.f, id = 0.f;
    int j = beg;
#define P2STEP(s_, w_) {                                                     \
        uint4 v = *(const uint4*)(P1 + (size_t)(s_) * 256 + 8 * p);          \
        oa = fmaf(w_.x, bflo(v.x), oa); ob = fmaf(w_.x, bfhi(v.x), ob);      \
        ia = fmaf(w_.y, bflo(v.y), ia); ib = fmaf(w_.y, bfhi(v.y), ib);      \
        oc = fmaf(w_.x, bflo(v.z), oc); od = fmaf(w_.x, bfhi(v.z), od);      \
        ic = fmaf(w_.y, bflo(v.w), ic); id = fmaf(w_.y, bfhi(v.w), id); }
    for (; j + 4 <= end; j += 4) {
        int s0 = src[j], s1 = src[j + 1], s2 = src[j + 2], s3 = src[j + 3];
        float2 w0 = w[j], w1 = w[j + 1], w2 = w[j + 2], w3 = w[j + 3];
        P2STEP(s0, w0); P2STEP(s1, w1); P2STEP(s2, w2); P2STEP(s3, w3);
    }
    for (; j < end; ++j) {
        int s = src[j]; float2 wv = w[j];
        P2STEP(s, wv);
    }
#undef P2STEP
    uint2 ux = *(const uint2*)(Xc + (size_t)node * 128 + 4 * p);
    float xa = bflo(ux.x), xb = bfhi(ux.x), xc = bflo(ux.y), xd = bfhi(ux.y);
    uint4 o;
    o.x = packbf(2.f * oa - xa, 2.f * ob - xb);
    o.y = packbf(2.f * ia - xa, 2.f * ib - xb);
    o.z = packbf(2.f * oc - xc, 2.f * od - xd);
    o.w = packbf(2.f * ic - xc, 2.f * id - xd);
    int tile = node >> 4, lr = node & 15, ck = p >> 2, q = p & 3;
    *(uint4*)(P2p + (((size_t)tile * 8 + ck) * 64 + q * 16 + lr) * 8) = o;
}

__global__ void prop1_64(const unsigned short* __restrict__ HR,
                         const int* __restrict__ rowptr, const int* __restrict__ src,
                         const float2* __restrict__ w,
                         unsigned short* __restrict__ Q1, unsigned short* __restrict__ Q1p,
                         int n) {
    int tid = blockIdx.x * blockDim.x + threadIdx.x;
    int lane = tid & 63;
    int node = ((tid >> 6) << 2) + (lane >> 4);
    int p = lane & 15;
    if (node >= n) return;
    int beg = rowptr[node], end = rowptr[node + 1];
    float ao0 = 0.f, ao1 = 0.f, ao2 = 0.f, ao3 = 0.f;
    float ai0 = 0.f, ai1 = 0.f, ai2 = 0.f, ai3 = 0.f;
    int j = beg;
#define Q1STEP(s_, w_) {                                                     \
        uint2 u = *(const uint2*)(HR + (size_t)(s_) * 64 + 4 * p);           \
        float c0 = bflo(u.x), c1 = bfhi(u.x), c2 = bflo(u.y), c3 = bfhi(u.y);\
        ao0 = fmaf(w_.x, c0, ao0); ao1 = fmaf(w_.x, c1, ao1);                \
        ao2 = fmaf(w_.x, c2, ao2); ao3 = fmaf(w_.x, c3, ao3);                \
        ai0 = fmaf(w_.y, c0, ai0); ai1 = fmaf(w_.y, c1, ai1);                \
        ai2 = fmaf(w_.y, c2, ai2); ai3 = fmaf(w_.y, c3, ai3); }
    for (; j + 4 <= end; j += 4) {
        int s0 = src[j], s1 = src[j + 1], s2 = src[j + 2], s3 = src[j + 3];
        float2 w0 = w[j], w1 = w[j + 1], w2 = w[j + 2], w3 = w[j + 3];
        Q1STEP(s0, w0); Q1STEP(s1, w1); Q1STEP(s2, w2); Q1STEP(s3, w3);
    }
    for (; j < end; ++j) {
        int s = src[j]; float2 wv = w[j];
        Q1STEP(s, wv);
    }
#undef Q1STEP
    uint4 o;
    o.x = packbf(ao0, ao1); o.y = packbf(ai0, ai1);
    o.z = packbf(ao2, ao3); o.w = packbf(ai2, ai3);
    *(uint4*)(Q1 + (size_t)node * 128 + 8 * p) = o;
    int tile = node >> 4, lr = node & 15, ck = p >> 2, q = p & 3;
    *(uint4*)(Q1p + (((size_t)tile * 4 + ck) * 64 + q * 16 + lr) * 8) = o;
}

__global__ void prop2_64(const unsigned short* __restrict__ Q1,
                         const unsigned short* __restrict__ HR,
                         const int* __restrict__ rowptr, const int* __restrict__ src,
                         const float2* __restrict__ w,
                         unsigned short* __restrict__ Q2p, int n) {
    int tid = blockIdx.x * blockDim.x + threadIdx.x;
    int lane = tid & 63;
    int node = ((tid >> 6) << 2) + (lane >> 4);
    int p = lane & 15;
    if (node >= n) return;
    int beg = rowptr[node], end = rowptr[node + 1];
    float oa = 0.f, ob = 0.f, oc = 0.f, od = 0.f;
    float ia = 0.f, ib = 0.f, ic = 0.f, id = 0.f;
    int j = beg;
#define Q2STEP(s_, w_) {                                                     \
        uint4 v = *(const uint4*)(Q1 + (size_t)(s_) * 128 + 8 * p);          \
        oa = fmaf(w_.x, bflo(v.x), oa); ob = fmaf(w_.x, bfhi(v.x), ob);      \
        ia = fmaf(w_.y, bflo(v.y), ia); ib = fmaf(w_.y, bfhi(v.y), ib);      \
        oc = fmaf(w_.x, bflo(v.z), oc); od = fmaf(w_.x, bfhi(v.z), od);      \
        ic = fmaf(w_.y, bflo(v.w), ic); id = fmaf(w_.y, bfhi(v.w), id); }
    for (; j + 4 <= end; j += 4) {
        int s0 = src[j], s1 = src[j + 1], s2 = src[j + 2], s3 = src[j + 3];
        float2 w0 = w[j], w1 = w[j + 1], w2 = w[j + 2], w3 = w[j + 3];
        Q2STEP(s0, w0); Q2STEP(s1, w1); Q2STEP(s2, w2); Q2STEP(s3, w3);
    }
    for (; j < end; ++j) {
        int s = src[j]; float2 wv = w[j];
        Q2STEP(s, wv);
    }
#undef Q2STEP
    uint2 ux = *(const uint2*)(HR + (size_t)node * 64 + 4 * p);
    float xa = bflo(ux.x), xb = bfhi(ux.x), xc = bflo(ux.y), xd = bfhi(ux.y);
    uint4 o;
    o.x = packbf(2.f * oa - xa, 2.f * ob - xb);
    o.y = packbf(2.f * ia - xa, 2.f * ib - xb);
    o.z = packbf(2.f * oc - xc, 2.f * od - xd);
    o.w = packbf(2.f * ic - xc, 2.f * id - xd);
    int tile = node >> 4, lr = node & 15, ck = p >> 2, q = p & 3;
    *(uint4*)(Q2p + (((size_t)tile * 4 + ck) * 64 + q * 16 + lr) * 8) = o;
}

// ---------------- MFMA GEMMs: fragment-packed A and B, no LDS, no barriers --
// All frag loads are coalesced 1KB wave loads: lane i reads 16B at base+16i.
// mfma_f32_16x16x32_bf16 C/D: col=lane&15, row=(lane>>4)*4+reg.

// ZR: block 64 rows x 128 cols; 4 waves each 64 rows x 32 cols (ngrp = wid).
__global__ __launch_bounds__(256) void gemm_zr_mfma(
    const unsigned short* __restrict__ XHp, const unsigned short* __restrict__ P1p,
    const unsigned short* __restrict__ P2p,
    const unsigned short* __restrict__ Wf, const float* __restrict__ bz,
    const float* __restrict__ br, const float* __restrict__ H,
    float* __restrict__ Zf, unsigned short* __restrict__ HR, int n) {
    int tid = threadIdx.x;
    int lane = tid & 63;
    int ngrp = tid >> 6;
    int rowbase = blockIdx.x * 64;
    int lr = lane & 15, quad = lane >> 4;

    int tiles[4];
#pragma unroll
    for (int mt = 0; mt < 4; ++mt) {
        int t = (rowbase >> 4) + mt;
        tiles[mt] = (t > N_TILES - 1) ? N_TILES - 1 : t;
    }

    f32x4 zero = {0.f, 0.f, 0.f, 0.f};
    f32x4 acc[4][2];
#pragma unroll
    for (int a = 0; a < 4; ++a)
#pragma unroll
        for (int b = 0; b < 2; ++b) acc[a][b] = zero;

#pragma unroll
    for (int ks = 0; ks < 20; ++ks) {
        const unsigned short* T = (ks < 4) ? XHp : (ks < 12) ? P1p : P2p;
        int ck = (ks < 4) ? ks : (ks < 12) ? ks - 4 : ks - 12;
        int nck = (ks < 4) ? 4 : 8;
        bf8 b0 = *(const bf8*)(Wf + (((size_t)ks * 8 + ngrp * 2 + 0) * 64 + lane) * 8);
        bf8 b1 = *(const bf8*)(Wf + (((size_t)ks * 8 + ngrp * 2 + 1) * 64 + lane) * 8);
#pragma unroll
        for (int mt = 0; mt < 4; ++mt) {
            bf8 a = *(const bf8*)(T + (((size_t)tiles[mt] * nck + ck) * 64 + lane) * 8);
            acc[mt][0] = __builtin_amdgcn_mfma_f32_16x16x32_bf16(a, b0, acc[mt][0], 0, 0, 0);
            acc[mt][1] = __builtin_amdgcn_mfma_f32_16x16x32_bf16(a, b1, acc[mt][1], 0, 0, 0);
        }
    }
#pragma unroll
    for (int mt = 0; mt < 4; ++mt)
#pragma unroll
        for (int reg = 0; reg < 4; ++reg) {
            int r = rowbase + mt * 16 + quad * 4 + reg;
            if (r >= n) continue;
#pragma unroll
            for (int nt = 0; nt < 2; ++nt) {
                int cidx = ngrp * 32 + nt * 16 + lr;
                float bias = (cidx < 64) ? bz[cidx] : br[cidx - 64];
                float v = acc[mt][nt][reg] + bias;
                float s = 1.f / (1.f + expf(-v));
                if (cidx < 64) {
                    Zf[(size_t)r * 64 + cidx] = s;
                } else {
                    int c2 = cidx - 64;
                    HR[(size_t)r * 64 + c2] = f2bfu(H[(size_t)r * 64 + c2] * s);
                }
            }
        }
}

// H~: block 128 rows x 64 cols; 4 waves = (mh = wid&1 row-half, ngrp = wid>>1),
// each 64 rows x 32 cols. ks: 0-1 XHp, 2-5 P1p, 6-9 P2p, 10-11 HR(row-major,
// strided — only 2/20), 12-15 Q1p, 16-19 Q2p.
__global__ __launch_bounds__(256) void gemm_h_mfma(
    const unsigned short* __restrict__ XHp, const unsigned short* __restrict__ P1p,
    const unsigned short* __restrict__ P2p, const unsigned short* __restrict__ HR,
    const unsigned short* __restrict__ Q1p, const unsigned short* __restrict__ Q2p,
    const unsigned short* __restrict__ Wf, const float* __restrict__ bh,
    const float* __restrict__ Zf, const float* __restrict__ H,
    float* __restrict__ out, int n) {
    int tid = threadIdx.x;
    int lane = tid & 63;
    int wid = tid >> 6;
    int mh = wid & 1, ngrp = wid >> 1;
    int rowbase = blockIdx.x * 128 + mh * 64;
    int lr = lane & 15, quad = lane >> 4;

    int tiles[4];
    const unsigned short* hrp[4];
#pragma unroll
    for (int mt = 0; mt < 4; ++mt) {
        int t = (rowbase >> 4) + mt;
        tiles[mt] = (t > N_TILES - 1) ? N_TILES - 1 : t;
        int r = rowbase + mt * 16 + lr;
        if (r >= n) r = n - 1;
        hrp[mt] = HR + (size_t)r * 64 + quad * 8;
    }

    f32x4 zero = {0.f, 0.f, 0.f, 0.f};
    f32x4 acc[4][2];
#pragma unroll
    for (int a = 0; a < 4; ++a)
#pragma unroll
        for (int b = 0; b < 2; ++b) acc[a][b] = zero;

#pragma unroll
    for (int ks = 0; ks < 20; ++ks) {
        bf8 b0 = *(const bf8*)(Wf + (((size_t)ks * 4 + ngrp * 2 + 0) * 64 + lane) * 8);
        bf8 b1 = *(const bf8*)(Wf + (((size_t)ks * 4 + ngrp * 2 + 1) * 64 + lane) * 8);
#pragma unroll
        for (int mt = 0; mt < 4; ++mt) {
            bf8 a;
            if (ks == 10 || ks == 11) {
                a = *(const bf8*)(hrp[mt] + (ks - 10) * 32);
            } else {
                const unsigned short* T = (ks < 2) ? XHp : (ks < 6) ? P1p :
                                          (ks < 10) ? P2p : (ks < 16) ? Q1p : Q2p;
                int ck = (ks < 2) ? ks : (ks < 6) ? ks - 2 : (ks < 10) ? ks - 6 :
                         (ks < 16) ? ks - 12 : ks - 16;
                int nck = (ks < 2) ? 4 : (ks < 10) ? 8 : 4;
                a = *(const bf8*)(T + (((size_t)tiles[mt] * nck + ck) * 64 + lane) * 8);
            }
            acc[mt][0] = __builtin_amdgcn_mfma_f32_16x16x32_bf16(a, b0, acc[mt][0], 0, 0, 0);
            acc[mt][1] = __builtin_amdgcn_mfma_f32_16x16x32_bf16(a, b1, acc[mt][1], 0, 0, 0);
        }
    }
#pragma unroll
    for (int mt = 0; mt < 4; ++mt)
#pragma unroll
        for (int reg = 0; reg < 4; ++reg) {
            int r = rowbase + mt * 16 + quad * 4 + reg;
            if (r >= n) continue;
#pragma unroll
            for (int nt = 0; nt < 2; ++nt) {
                int cidx = ngrp * 32 + nt * 16 + lr;
                float ht = tanhf(acc[mt][nt][reg] + bh[cidx]);
                float z = Zf[(size_t)r * 64 + cidx];
                float h_old = H[(size_t)r * 64 + cidx];
                out[(size_t)r * 64 + cidx] = z * h_old + (1.f - z) * ht;
            }
        }
}

// ---------------- launch ----------------

static inline size_t rup(size_t x) { return (x + 63) & ~(size_t)63; }

extern "C" void kernel_launch(void* const* d_in, const int* in_sizes, int n_in,
                              void* d_out, int out_size, void* d_ws, size_t ws_size,
                              hipStream_t stream) {
    const float* X  = (const float*)d_in[0];
    const int*   EI = (const int*)d_in[1];
    const float* H  = (const float*)d_in[2];
    const float* Wz = (const float*)d_in[3];
    const float* bz = (const float*)d_in[4];
    const float* Wr = (const float*)d_in[5];
    const float* br = (const float*)d_in[6];
    const float* Wh = (const float*)d_in[7];
    const float* bh = (const float*)d_in[8];
    float* out = (float*)d_out;

    const int* row = EI;
    const int* col = EI + N_EDGES;

    char* ws = (char*)d_ws;
    size_t off = 0;
    auto carve = [&](size_t bytes) { void* p = ws + off; off += rup(bytes); return p; };

    int*   deg_out   = (int*)carve(N_NODES * 4);
    int*   deg_in    = (int*)carve(N_NODES * 4);
    int*   rowptr    = (int*)carve((N_NODES + 1) * 4);
    int*   cursor    = (int*)carve(N_NODES * 4);
    int*   blocksums = (int*)carve(64 * 4);
    float2* winv     = (float2*)carve(N_NODES * 8);
    int*   csr_src   = (int*)carve(N_EDGES * 4);
    float2* csr_w    = (float2*)carve(N_EDGES * 8);
    unsigned short* XH  = (unsigned short*)carve((size_t)N_NODES * 128 * 2);  // dead after prop2_128
    unsigned short* P1  = (unsigned short*)carve((size_t)N_NODES * 256 * 2);  // dead after prop2_128
    unsigned short* XHp = (unsigned short*)carve((size_t)N_TILES * 4 * 512 * 2);
    unsigned short* P1p = (unsigned short*)carve((size_t)N_TILES * 8 * 512 * 2);
    unsigned short* P2p = (unsigned short*)carve((size_t)N_TILES * 8 * 512 * 2);
    unsigned short* HR  = (unsigned short*)carve((size_t)N_NODES * 64 * 2);
    float* Zf           = (float*)carve((size_t)N_NODES * 64 * 4);
    unsigned short* Wzrf = (unsigned short*)carve(20 * 8 * 64 * 8 * 2);
    unsigned short* Whf  = (unsigned short*)carve(20 * 4 * 64 * 8 * 2);

    // Aliases (regions dead by the time these are written):
    unsigned short* Q1  = XH;                                  // 12.8 MB, same size
    unsigned short* Q1p = P1;                                  // first 12.8 MB of P1
    unsigned short* Q2p = P1 + (size_t)N_TILES * 4 * 512;      // second 12.8 MB of P1

    hipMemsetAsync(deg_out, 0, rup(N_NODES * 4) + rup(N_NODES * 4), stream);
    count_deg<<<(N_EDGES + 255) / 256, 256, 0, stream>>>(row, col, deg_out, deg_in, N_EDGES);

    int nblk = (N_NODES + 1023) / 1024;
    scan_block<<<nblk, 1024, 0, stream>>>(deg_in, rowptr, blocksums, N_NODES);
    scan_sums<<<1, 64, 0, stream>>>(blocksums, nblk);
    scan_add<<<(N_NODES + 1 + 255) / 256, 256, 0, stream>>>(rowptr, blocksums, cursor,
                                                            deg_out, deg_in, winv, N_NODES, N_EDGES);

    build_csr<<<(N_EDGES + 255) / 256, 256, 0, stream>>>(row, col, winv, cursor,
                                                         csr_src, csr_w, N_EDGES);

    pack_weights<<<(20 * 8 * 64 * 8 + 20 * 4 * 64 * 8 + 255) / 256, 256, 0, stream>>>(
        Wz, Wr, Wh, Wzrf, Whf);

    concat_xh<<<(N_NODES * 16 + 255) / 256, 256, 0, stream>>>(X, H, XH, XHp, N_NODES);

    // props on XH: 2 nodes/wave
    int blocks_p128 = (((N_NODES + 1) / 2) * 64 + 255) / 256;
    prop1_128<<<blocks_p128, 256, 0, stream>>>(XH, rowptr, csr_src, csr_w, P1, P1p, N_NODES);
    prop2_128<<<blocks_p128, 256, 0, stream>>>(P1, XH, rowptr, csr_src, csr_w, P2p, N_NODES);

    // Z|R GEMM -> Zf, HR   (XH, P1 row-major now dead)
    int zr_blocks = (N_NODES + 63) / 64;
    gemm_zr_mfma<<<zr_blocks, 256, 0, stream>>>(XHp, P1p, P2p, Wzrf, bz, br, H, Zf, HR, N_NODES);

    // props on HR: 4 nodes/wave
    int blocks_p64 = (((N_NODES + 3) / 4) * 64 + 255) / 256;
    prop1_64<<<blocks_p64, 256, 0, stream>>>(HR, rowptr, csr_src, csr_w, Q1, Q1p, N_NODES);
    prop2_64<<<blocks_p64, 256, 0, stream>>>(Q1, HR, rowptr, csr_src, csr_w, Q2p, N_NODES);

    // H~ GEMM + GRU mix -> out
    int h_blocks = (N_NODES + 127) / 128;
    gemm_h_mfma<<<h_blocks, 256, 0, stream>>>(XHp, P1p, P2p, HR, Q1p, Q2p,
                                              Whf, bh, Zf, H, out, N_NODES);
}